// Round 1
// 572.309 us; speedup vs baseline: 1.0466x; 1.0466x over previous
//
#include <hip/hip_runtime.h>
#include <stdint.h>

#define BATCH 32
#define HWD 224
#define HP 14
#define NP (BATCH * HP * HP)   // 6272 patches = 49 * 128
#define DIM 768
#define K0 512
#define K1 2048
#define K2 8192

typedef unsigned long long ull;
typedef unsigned int uint;
typedef __attribute__((ext_vector_type(8))) short bf16x8;
typedef __attribute__((ext_vector_type(4))) float f32x4;

__device__ __forceinline__ uint fkey(float f) {
    uint u = __float_as_uint(f);
    return (u & 0x80000000u) ? ~u : (u | 0x80000000u);  // monotone fp32 -> u32
}
__device__ __forceinline__ short f2bf(float f) {       // round-to-nearest-even bf16
    uint u = __float_as_uint(f);
    uint r = (u + 0x7fffu + ((u >> 16) & 1u)) >> 16;
    return (short)r;
}
__device__ __forceinline__ float bf2f(short h) {
    return __uint_as_float(((uint)(unsigned short)h) << 16);
}
__device__ __forceinline__ ull umin64(ull a, ull b) { return a < b ? a : b; }
__device__ __forceinline__ ull umax64(ull a, ull b) { return a > b ? a : b; }

// ---------------- patchify + bf16 hi/lo split (residual kept as hi/lo pair) ----------------
__global__ void patchify_split_kernel(const float* __restrict__ data,
                                      short* __restrict__ xh, short* __restrict__ xl) {
    int gid = blockIdx.x * 256 + threadIdx.x;   // covers NP*DIM exactly
    int d = gid % DIM;
    int p = gid / DIM;
    int b = p / 196; int t = p % 196; int i = t / 14, j = t % 14;
    int ch = d >> 8; int r = d & 255; int py = r >> 4; int px = r & 15;
    float v = data[((b * 3 + ch) * HWD + i * 16 + py) * HWD + j * 16 + px];
    short h = f2bf(v);
    xh[gid] = h;
    xl[gid] = f2bf(v - bf2f(h));
}

// ---------------- center prep: bf16 hi/lo + row norms ----------------
__global__ void cprep_kernel(const float* __restrict__ c, short* __restrict__ ch,
                             short* __restrict__ cl, float* __restrict__ nrm) {
    int lane = threadIdx.x & 63;
    int row = blockIdx.x * 4 + (threadIdx.x >> 6);
    const float* src = c + (size_t)row * DIM;
    float s = 0.f;
    #pragma unroll
    for (int i = 0; i < 12; ++i) {
        int d = lane + i * 64;
        float v = src[d];
        short h = f2bf(v);
        ch[(size_t)row * DIM + d] = h;
        cl[(size_t)row * DIM + d] = f2bf(v - bf2f(h));
        s += v * v;
    }
    #pragma unroll
    for (int off = 32; off; off >>= 1) s += __shfl_xor(s, off, 64);
    if (lane == 0) nrm[row] = s;
}

// ---------------- MFMA classify (verified 16x16x32 layouts) ----------------
// 2-term split: x.c ~= xh.ch + xh.cl  (error = xl.c, sigma ~0.02 on the dot).
// Block 256 thr = 4 waves (wm = w&1 selects m-half, wn = w>>1 selects n-half).
// Block tile: M=128, N=2*NHT*16. Wave tile: 64m x NHT*16 n of 16x16 tiles.
// LDS in FRAGMENT ORDER: slot(16B) = region + tile*64 + lane holds
// row (tile*16 + (lane&15)), elements [dc + (lane>>4)*8, +8).
// A-frag: A[m=lane&15][k=(lane>>4)*8+j]; B-frag from B^T rows (same shape);
// C/D: col=lane&15, row=(lane>>4)*4+reg.  [all measured: learn_hip m89-m97]
//
// R1 change: double-buffered LDS + prefetch-issue-before-compute (T3 minimum
// 2-phase recipe). Stage for tile t+1 is issued BEFORE the MFMAs of tile t,
// so the compiler's vmcnt(0)-drain at the single end-of-iteration barrier
// waits on loads that already had ~1240 MFMA cycles to land. One barrier per
// K-step instead of two.
template<int NHT>
__global__ __launch_bounds__(256, 2) void classify16(
    const short* __restrict__ xh,
    const short* __restrict__ chv, const short* __restrict__ clv,
    const float* __restrict__ nrm,
    ull* __restrict__ partB, ull* __restrict__ partS2)
{
    constexpr int NB = 2 * NHT * 16;        // block N (256 or 128)
    constexpr int CH0 = 512;                // ch slot base
    constexpr int CL0 = 512 + 128 * NHT;    // cl slot base
    constexpr int SLOTS = 512 + 256 * NHT;  // slots per buffer
    constexpr int NJ = (8 + 4 * NHT) / 4;   // staging instrs per wave (10 or 6)
    __shared__ __align__(16) short lds[2 * SLOTS * 8];   // 80 KB / 48 KB (dbuf)

    const int tid = threadIdx.x;
    const int lane = tid & 63;
    const int w = tid >> 6;
    const int wm = w & 1, wn = w >> 1;
    const int pbase = blockIdx.x * 128;
    const int n0 = blockIdx.y * NB;

    // staging descriptors: group g covers slots [region + t*64, +64)
    const short* gp[NJ];
    int ls[NJ];
    #pragma unroll
    for (int j = 0; j < NJ; ++j) {
        int g = j * 4 + w;
        const short* base; int rb, sb, t;
        if (g < 8)              { base = xh;  rb = pbase; sb = 0;    t = g; }
        else if (g < 8 + 2*NHT) { base = chv; rb = n0;    sb = CH0;  t = g - 8; }
        else                    { base = clv; rb = n0;    sb = CL0;  t = g - 8 - 2*NHT; }
        gp[j] = base + (size_t)(rb + t * 16 + (lane & 15)) * DIM + ((lane >> 4) * 8);
        ls[j] = sb + t * 64;
    }

    f32x4 acc[4][NHT];
    #pragma unroll
    for (int i = 0; i < 4; ++i)
        #pragma unroll
        for (int u = 0; u < NHT; ++u) acc[i][u] = (f32x4){0.f, 0.f, 0.f, 0.f};

    auto stage = [&](int buf, int dc) {
        const int off = buf * SLOTS;
        #pragma unroll
        for (int j = 0; j < NJ; ++j) {
            __builtin_amdgcn_global_load_lds(
                (const __attribute__((address_space(1))) void*)(gp[j] + dc),
                (__attribute__((address_space(3))) void*)(lds + (size_t)(off + ls[j]) * 8),
                16, 0, 0);
        }
    };
    auto compute = [&](int buf) {
        const bf16x8* Lc = (const bf16x8*)lds + buf * SLOTS;
        bf16x8 fxh[4];
        #pragma unroll
        for (int i = 0; i < 4; ++i)
            fxh[i] = Lc[(wm * 4 + i) * 64 + lane];
        #pragma unroll
        for (int u = 0; u < NHT; ++u) {
            bf16x8 fch = Lc[CH0 + (wn * NHT + u) * 64 + lane];
            bf16x8 fcl = Lc[CL0 + (wn * NHT + u) * 64 + lane];
            #pragma unroll
            for (int i = 0; i < 4; ++i) {
                acc[i][u] = __builtin_amdgcn_mfma_f32_16x16x32_bf16(fxh[i], fch, acc[i][u], 0, 0, 0);
                acc[i][u] = __builtin_amdgcn_mfma_f32_16x16x32_bf16(fxh[i], fcl, acc[i][u], 0, 0, 0);
            }
        }
    };

    // prologue: stage tile 0 into buf 0 (compiler emits vmcnt(0) before barrier)
    stage(0, 0);
    __syncthreads();

    int cur = 0;
    for (int dc = 32; dc < DIM; dc += 32) {
        stage(cur ^ 1, dc);     // issue next tile's loads BEFORE computing current
        compute(cur);
        __syncthreads();        // drains vmcnt(0): prefetch landed + reads done
        cur ^= 1;
    }
    compute(cur);               // tail tile, nothing in flight

    // epilogue: per-row top-2 over this block's wave-half (NB/2 centers)
    float nor[NHT]; uint ncol[NHT];
    #pragma unroll
    for (int u = 0; u < NHT; ++u) {
        ncol[u] = (uint)(n0 + (wn * NHT + u) * 16 + (lane & 15));
        nor[u] = nrm[ncol[u]];
    }
    #pragma unroll
    for (int i = 0; i < 4; ++i) {
        #pragma unroll
        for (int reg = 0; reg < 4; ++reg) {
            ull b = ~0ull, s2 = ~0ull;
            #pragma unroll
            for (int u = 0; u < NHT; ++u) {
                float s = fmaf(-2.f, acc[i][u][reg], nor[u]);
                ull pk = ((ull)fkey(s) << 32) | ncol[u];
                ull nb = umin64(b, pk);
                s2 = umin64(s2, umax64(b, pk));
                b = nb;
            }
            #pragma unroll
            for (int off = 1; off <= 8; off <<= 1) {   // reduce across lane&15
                ull ob = __shfl_xor(b, off, 64);
                ull os2 = __shfl_xor(s2, off, 64);
                ull nb = umin64(b, ob);
                s2 = umin64(umin64(s2, os2), umax64(b, ob));
                b = nb;
            }
            if ((lane & 15) == 0) {
                int row = pbase + (wm * 4 + i) * 16 + (lane >> 4) * 4 + reg;
                size_t o = (size_t)row * 64 + blockIdx.y * 2 + wn;
                partB[o] = b;
                partS2[o] = s2;
            }
        }
    }
}

// ---------------- merge partials + exact fp32 top-4 rescue + residual update ----------------
__global__ void merge_rescue_update(
    short* __restrict__ xh, short* __restrict__ xl,
    const float* __restrict__ cent, const float* __restrict__ nrm,
    const ull* __restrict__ partB, const ull* __restrict__ partS2,
    int nsplit, int* __restrict__ cls)
{
    int lane = threadIdx.x & 63;
    int p = blockIdx.x * 4 + (threadIdx.x >> 6);
    ull a = ~0ull, c = ~0ull;
    if (lane < nsplit) {
        a = partB[(size_t)p * 64 + lane];
        c = partS2[(size_t)p * 64 + lane];
    }
    // extract top-4 candidates (packed keys unique: idx appears once)
    int idx[4];
    #pragma unroll
    for (int r = 0; r < 4; ++r) {
        ull m = a;
        #pragma unroll
        for (int off = 32; off; off >>= 1) m = umin64(m, __shfl_xor(m, off, 64));
        idx[r] = (int)(m & 0xFFFFFFFFull);
        if (a == m) { a = c; c = ~0ull; }   // pop from owning lane
    }
    // x reconstructed once into registers
    float xv[12];
    #pragma unroll
    for (int i = 0; i < 12; ++i) {
        int d = lane + i * 64;
        xv[i] = bf2f(xh[(size_t)p * DIM + d]) + bf2f(xl[(size_t)p * DIM + d]);
    }
    float dot[4] = {0.f, 0.f, 0.f, 0.f};
    #pragma unroll
    for (int r = 0; r < 4; ++r) {
        const float* cr = cent + (size_t)idx[r] * DIM;
        #pragma unroll
        for (int i = 0; i < 12; ++i) dot[r] = fmaf(xv[i], cr[lane + i * 64], dot[r]);
    }
    #pragma unroll
    for (int r = 0; r < 4; ++r)
        #pragma unroll
        for (int off = 32; off; off >>= 1) dot[r] += __shfl_xor(dot[r], off, 64);
    ull best = ~0ull;
    #pragma unroll
    for (int r = 0; r < 4; ++r) {
        float sc = fmaf(-2.f, dot[r], nrm[idx[r]]);
        best = umin64(best, ((ull)fkey(sc) << 32) | (uint)idx[r]);  // ties -> lower idx
    }
    int cw = (int)(best & 0xFFFFFFFFull);
    if (lane == 0) cls[p] = cw;
    const float* cwr = cent + (size_t)cw * DIM;
    #pragma unroll
    for (int i = 0; i < 12; ++i) {
        int d = lane + i * 64;
        float nx = xv[i] - cwr[d];
        short h = f2bf(nx);
        xh[(size_t)p * DIM + d] = h;
        xl[(size_t)p * DIM + d] = f2bf(nx - bf2f(h));
    }
}

// ---------------- embed + diff outputs (LDS transpose, coalesced writes) ----------------
__global__ void embdiff_kernel(const short* __restrict__ xh, const short* __restrict__ xl,
    const int* __restrict__ cls0, const int* __restrict__ cls1, const int* __restrict__ cls2,
    const float* __restrict__ e0, const float* __restrict__ e1, const float* __restrict__ e2,
    float* __restrict__ out)
{
    __shared__ float s[196][65];
    int b = blockIdx.x / 12;
    int dc = (blockIdx.x % 12) * 64;
    int tid = threadIdx.x;
    int dl = tid & 63;
    // embed
    for (int it = 0; it < 49; ++it) {
        int pl = it * 4 + (tid >> 6);
        int p = b * 196 + pl;
        int d = dc + dl;
        s[pl][dl] = e0[(size_t)cls0[p] * DIM + d] + e1[(size_t)cls1[p] * DIM + d]
                  + e2[(size_t)cls2[p] * DIM + d];
    }
    __syncthreads();
    if (tid < 196) {
        for (int d = 0; d < 64; ++d)
            out[((size_t)b * DIM + dc + d) * 196 + tid] = s[tid][d];
    }
    __syncthreads();
    // diff (residual = xh + xl)
    for (int it = 0; it < 49; ++it) {
        int pl = it * 4 + (tid >> 6);
        size_t o = (size_t)(b * 196 + pl) * DIM + dc + dl;
        s[pl][dl] = bf2f(xh[o]) + bf2f(xl[o]);
    }
    __syncthreads();
    if (tid < 196) {
        float* od = out + 2 * (size_t)NP * DIM;
        for (int d = 0; d < 64; ++d)
            od[((size_t)b * DIM + dc + d) * 196 + tid] = s[tid][d];
    }
}

// ---------------- img_sum output ----------------
__global__ void img_kernel(
    const int* __restrict__ cls0, const int* __restrict__ cls1, const int* __restrict__ cls2,
    const float* __restrict__ c0, const float* __restrict__ c1, const float* __restrict__ c2,
    float* __restrict__ out)
{
    __shared__ float s[14][256];
    int bi = blockIdx.x;
    int b = bi / 42; int rem = bi % 42; int ch = rem / 14; int i = rem % 14;
    int tid = threadIdx.x;
    for (int j = 0; j < 14; ++j) {
        int p = b * 196 + i * 14 + j;
        int d = ch * 256 + tid;
        s[j][tid] = c0[(size_t)cls0[p] * DIM + d] + c1[(size_t)cls1[p] * DIM + d]
                  + c2[(size_t)cls2[p] * DIM + d];
    }
    __syncthreads();
    float* oi = out + (size_t)NP * DIM;
    if (tid < 224) {
        int j = tid >> 4, px = tid & 15;
        for (int py = 0; py < 16; ++py)
            oi[(((size_t)b * 3 + ch) * HWD + i * 16 + py) * HWD + tid] = s[j][py * 16 + px];
    }
}

extern "C" void kernel_launch(void* const* d_in, const int* in_sizes, int n_in,
                              void* d_out, int out_size, void* d_ws, size_t ws_size,
                              hipStream_t stream) {
    const float* data = (const float*)d_in[0];
    const float* c0 = (const float*)d_in[1];
    const float* c1 = (const float*)d_in[2];
    const float* c2 = (const float*)d_in[3];
    const float* e0 = (const float*)d_in[4];
    const float* e1 = (const float*)d_in[5];
    const float* e2 = (const float*)d_in[6];
    float* out = (float*)d_out;

    char* w = (char*)d_ws;
    short* xh = (short*)w;    w += (size_t)NP * DIM * 2;      // 9.63 MB
    short* xl = (short*)w;    w += (size_t)NP * DIM * 2;      // 9.63 MB
    short* chB = (short*)w;   w += (size_t)K2 * DIM * 2;      // 12.58 MB
    short* clB = (short*)w;   w += (size_t)K2 * DIM * 2;      // 12.58 MB
    float* nrm = (float*)w;   w += (size_t)K2 * 4;            // 32 KB
    ull* partB = (ull*)w;     w += (size_t)NP * 64 * 8;       // 3.21 MB
    ull* partS2 = (ull*)w;    w += (size_t)NP * 64 * 8;       // 3.21 MB
    int* cls0 = (int*)w;      w += (size_t)NP * 4;
    int* cls1 = (int*)w;      w += (size_t)NP * 4;
    int* cls2 = (int*)w;      w += (size_t)NP * 4;
    // total ~48.6 MiB

    patchify_split_kernel<<<(NP * DIM) / 256, 256, 0, stream>>>(data, xh, xl);

    // level 0: K=512, N/block=128 (NHT=4), grid (49,4) -> 8 partials
    cprep_kernel<<<K0 / 4, 256, 0, stream>>>(c0, chB, clB, nrm);
    classify16<4><<<dim3(NP / 128, 4), 256, 0, stream>>>(xh, chB, clB, nrm, partB, partS2);
    merge_rescue_update<<<NP / 4, 256, 0, stream>>>(xh, xl, c0, nrm, partB, partS2, 8, cls0);

    // level 1: K=2048, N/block=256 (NHT=8), grid (49,8) -> 16 partials
    cprep_kernel<<<K1 / 4, 256, 0, stream>>>(c1, chB, clB, nrm);
    classify16<8><<<dim3(NP / 128, 8), 256, 0, stream>>>(xh, chB, clB, nrm, partB, partS2);
    merge_rescue_update<<<NP / 4, 256, 0, stream>>>(xh, xl, c1, nrm, partB, partS2, 16, cls1);

    // level 2: K=8192, N/block=256 (NHT=8), grid (49,32) -> 64 partials
    cprep_kernel<<<K2 / 4, 256, 0, stream>>>(c2, chB, clB, nrm);
    classify16<8><<<dim3(NP / 128, 32), 256, 0, stream>>>(xh, chB, clB, nrm, partB, partS2);
    merge_rescue_update<<<NP / 4, 256, 0, stream>>>(xh, xl, c2, nrm, partB, partS2, 64, cls2);

    embdiff_kernel<<<BATCH * 12, 256, 0, stream>>>(xh, xl, cls0, cls1, cls2, e0, e1, e2, out);
    img_kernel<<<BATCH * 3 * 14, 256, 0, stream>>>(cls0, cls1, cls2, c0, c1, c2, out);
}

// Round 4
// 570.144 us; speedup vs baseline: 1.0506x; 1.0038x over previous
//
#include <hip/hip_runtime.h>
#include <stdint.h>

#define BATCH 32
#define HWD 224
#define HP 14
#define NP (BATCH * HP * HP)   // 6272 patches = 49 * 128
#define DIM 768
#define K0 512
#define K1 2048
#define K2 8192

typedef unsigned long long ull;
typedef unsigned int uint;
typedef __attribute__((ext_vector_type(8))) short bf16x8;
typedef __attribute__((ext_vector_type(4))) float f32x4;

__device__ __forceinline__ uint fkey(float f) {
    uint u = __float_as_uint(f);
    return (u & 0x80000000u) ? ~u : (u | 0x80000000u);  // monotone fp32 -> u32
}
__device__ __forceinline__ short f2bf(float f) {       // round-to-nearest-even bf16
    uint u = __float_as_uint(f);
    uint r = (u + 0x7fffu + ((u >> 16) & 1u)) >> 16;
    return (short)r;
}
__device__ __forceinline__ float bf2f(short h) {
    return __uint_as_float(((uint)(unsigned short)h) << 16);
}
__device__ __forceinline__ ull umin64(ull a, ull b) { return a < b ? a : b; }
__device__ __forceinline__ ull umax64(ull a, ull b) { return a > b ? a : b; }

// ---------------- patchify + bf16 hi/lo split (residual kept as hi/lo pair) ----------------
__global__ void patchify_split_kernel(const float* __restrict__ data,
                                      short* __restrict__ xh, short* __restrict__ xl) {
    int gid = blockIdx.x * 256 + threadIdx.x;   // covers NP*DIM exactly
    int d = gid % DIM;
    int p = gid / DIM;
    int b = p / 196; int t = p % 196; int i = t / 14, j = t % 14;
    int ch = d >> 8; int r = d & 255; int py = r >> 4; int px = r & 15;
    float v = data[((b * 3 + ch) * HWD + i * 16 + py) * HWD + j * 16 + px];
    short h = f2bf(v);
    xh[gid] = h;
    xl[gid] = f2bf(v - bf2f(h));
}

// ---------------- center prep: bf16 hi/lo + row norms ----------------
__global__ void cprep_kernel(const float* __restrict__ c, short* __restrict__ ch,
                             short* __restrict__ cl, float* __restrict__ nrm) {
    int lane = threadIdx.x & 63;
    int row = blockIdx.x * 4 + (threadIdx.x >> 6);
    const float* src = c + (size_t)row * DIM;
    float s = 0.f;
    #pragma unroll
    for (int i = 0; i < 12; ++i) {
        int d = lane + i * 64;
        float v = src[d];
        short h = f2bf(v);
        ch[(size_t)row * DIM + d] = h;
        cl[(size_t)row * DIM + d] = f2bf(v - bf2f(h));
        s += v * v;
    }
    #pragma unroll
    for (int off = 32; off; off >>= 1) s += __shfl_xor(s, off, 64);
    if (lane == 0) nrm[row] = s;
}

// ---------------- MFMA classify (verified 16x16x32 layouts) ----------------
// 2-term split: x.c ~= xh.ch + xh.cl  (error = xl.c, sigma ~0.02 on the dot).
// Block 256 thr = 4 waves (wm = w&1 selects m-half, wn = w>>1 selects n-half).
// Block tile: M=128, N=2*NHT*16. Wave tile: 64m x NHT*16 n of 16x16 tiles.
// LDS in FRAGMENT ORDER: slot(16B) = region + tile*64 + lane holds
// row (tile*16 + (lane&15)), elements [dc + (lane>>4)*8, +8).
// A-frag: A[m=lane&15][k=(lane>>4)*8+j]; B-frag from B^T rows (same shape);
// C/D: col=lane&15, row=(lane>>4)*4+reg.  [all measured: learn_hip m89-m97]
//
// R1: double-buffered LDS + prefetch-issue-before-compute (T3 2-phase).
// R2: XCD-aware bijective block swizzle (T1). Physical linear id P round-robins
// XCDs (P%8); remap so each XCD owns a contiguous y-chunk: all 49 x-blocks
// sharing one center slice run consecutively on ONE XCD -> the ~0.8-3 MB
// center slice stays resident in that XCD's 4 MB L2 instead of being
// re-streamed from L3 by all 8 XCDs (1.23 GB logical B-traffic was the
// 262 MB FETCH_SIZE / latency source). Identity when gridDim.y % 8 != 0 (L0).
template<int NHT>
__global__ __launch_bounds__(256, 2) void classify16(
    const short* __restrict__ xh,
    const short* __restrict__ chv, const short* __restrict__ clv,
    const float* __restrict__ nrm,
    ull* __restrict__ partB, ull* __restrict__ partS2)
{
    constexpr int NB = 2 * NHT * 16;        // block N (256 or 128)
    constexpr int CH0 = 512;                // ch slot base
    constexpr int CL0 = 512 + 128 * NHT;    // cl slot base
    constexpr int SLOTS = 512 + 256 * NHT;  // slots per buffer
    constexpr int NJ = (8 + 4 * NHT) / 4;   // staging instrs per wave (10 or 6)
    constexpr int GX = NP / 128;            // 49 x-blocks
    __shared__ __align__(16) short lds[2 * SLOTS * 8];   // 80 KB / 48 KB (dbuf)

    // T1 bijective XCD swizzle: valid because GX*gridY % 8 == 0 for L1/L2.
    int bx = blockIdx.x, by = blockIdx.y;
    if ((gridDim.y & 7) == 0) {
        int P = blockIdx.x + GX * blockIdx.y;
        int xcd = P & 7;
        int wofs = P >> 3;                  // 0 .. GX*gridY/8 - 1
        int ypx = gridDim.y >> 3;           // y-slices per XCD
        by = xcd * ypx + wofs / GX;
        bx = wofs % GX;
    }

    const int tid = threadIdx.x;
    const int lane = tid & 63;
    const int w = tid >> 6;
    const int wm = w & 1, wn = w >> 1;
    const int pbase = bx * 128;
    const int n0 = by * NB;

    // staging descriptors: group g covers slots [region + t*64, +64)
    const short* gp[NJ];
    int ls[NJ];
    #pragma unroll
    for (int j = 0; j < NJ; ++j) {
        int g = j * 4 + w;
        const short* base; int rb, sb, t;
        if (g < 8)              { base = xh;  rb = pbase; sb = 0;    t = g; }
        else if (g < 8 + 2*NHT) { base = chv; rb = n0;    sb = CH0;  t = g - 8; }
        else                    { base = clv; rb = n0;    sb = CL0;  t = g - 8 - 2*NHT; }
        gp[j] = base + (size_t)(rb + t * 16 + (lane & 15)) * DIM + ((lane >> 4) * 8);
        ls[j] = sb + t * 64;
    }

    f32x4 acc[4][NHT];
    #pragma unroll
    for (int i = 0; i < 4; ++i)
        #pragma unroll
        for (int u = 0; u < NHT; ++u) acc[i][u] = (f32x4){0.f, 0.f, 0.f, 0.f};

    auto stage = [&](int buf, int dc) {
        const int off = buf * SLOTS;
        #pragma unroll
        for (int j = 0; j < NJ; ++j) {
            __builtin_amdgcn_global_load_lds(
                (const __attribute__((address_space(1))) void*)(gp[j] + dc),
                (__attribute__((address_space(3))) void*)(lds + (size_t)(off + ls[j]) * 8),
                16, 0, 0);
        }
    };
    auto compute = [&](int buf) {
        const bf16x8* Lc = (const bf16x8*)lds + buf * SLOTS;
        bf16x8 fxh[4];
        #pragma unroll
        for (int i = 0; i < 4; ++i)
            fxh[i] = Lc[(wm * 4 + i) * 64 + lane];
        #pragma unroll
        for (int u = 0; u < NHT; ++u) {
            bf16x8 fch = Lc[CH0 + (wn * NHT + u) * 64 + lane];
            bf16x8 fcl = Lc[CL0 + (wn * NHT + u) * 64 + lane];
            #pragma unroll
            for (int i = 0; i < 4; ++i) {
                acc[i][u] = __builtin_amdgcn_mfma_f32_16x16x32_bf16(fxh[i], fch, acc[i][u], 0, 0, 0);
                acc[i][u] = __builtin_amdgcn_mfma_f32_16x16x32_bf16(fxh[i], fcl, acc[i][u], 0, 0, 0);
            }
        }
    };

    // prologue: stage tile 0 into buf 0 (compiler emits vmcnt(0) before barrier)
    stage(0, 0);
    __syncthreads();

    int cur = 0;
    for (int dc = 32; dc < DIM; dc += 32) {
        stage(cur ^ 1, dc);     // issue next tile's loads BEFORE computing current
        compute(cur);
        __syncthreads();        // drains vmcnt(0): prefetch landed + reads done
        cur ^= 1;
    }
    compute(cur);               // tail tile, nothing in flight

    // epilogue: per-row top-2 over this block's wave-half (NB/2 centers)
    float nor[NHT]; uint ncol[NHT];
    #pragma unroll
    for (int u = 0; u < NHT; ++u) {
        ncol[u] = (uint)(n0 + (wn * NHT + u) * 16 + (lane & 15));
        nor[u] = nrm[ncol[u]];
    }
    #pragma unroll
    for (int i = 0; i < 4; ++i) {
        #pragma unroll
        for (int reg = 0; reg < 4; ++reg) {
            ull b = ~0ull, s2 = ~0ull;
            #pragma unroll
            for (int u = 0; u < NHT; ++u) {
                float s = fmaf(-2.f, acc[i][u][reg], nor[u]);
                ull pk = ((ull)fkey(s) << 32) | ncol[u];
                ull nb = umin64(b, pk);
                s2 = umin64(s2, umax64(b, pk));
                b = nb;
            }
            #pragma unroll
            for (int off = 1; off <= 8; off <<= 1) {   // reduce across lane&15
                ull ob = __shfl_xor(b, off, 64);
                ull os2 = __shfl_xor(s2, off, 64);
                ull nb = umin64(b, ob);
                s2 = umin64(umin64(s2, os2), umax64(b, ob));
                b = nb;
            }
            if ((lane & 15) == 0) {
                int row = pbase + (wm * 4 + i) * 16 + (lane >> 4) * 4 + reg;
                size_t o = (size_t)row * 64 + (size_t)by * 2 + wn;
                partB[o] = b;
                partS2[o] = s2;
            }
        }
    }
}

// ---------------- merge partials + exact fp32 top-4 rescue + residual update ----------------
__global__ void merge_rescue_update(
    short* __restrict__ xh, short* __restrict__ xl,
    const float* __restrict__ cent, const float* __restrict__ nrm,
    const ull* __restrict__ partB, const ull* __restrict__ partS2,
    int nsplit, int* __restrict__ cls)
{
    int lane = threadIdx.x & 63;
    int p = blockIdx.x * 4 + (threadIdx.x >> 6);
    ull a = ~0ull, c = ~0ull;
    if (lane < nsplit) {
        a = partB[(size_t)p * 64 + lane];
        c = partS2[(size_t)p * 64 + lane];
    }
    // extract top-4 candidates (packed keys unique: idx appears once)
    int idx[4];
    #pragma unroll
    for (int r = 0; r < 4; ++r) {
        ull m = a;
        #pragma unroll
        for (int off = 32; off; off >>= 1) m = umin64(m, __shfl_xor(m, off, 64));
        idx[r] = (int)(m & 0xFFFFFFFFull);
        if (a == m) { a = c; c = ~0ull; }   // pop from owning lane
    }
    // x reconstructed once into registers
    float xv[12];
    #pragma unroll
    for (int i = 0; i < 12; ++i) {
        int d = lane + i * 64;
        xv[i] = bf2f(xh[(size_t)p * DIM + d]) + bf2f(xl[(size_t)p * DIM + d]);
    }
    float dot[4] = {0.f, 0.f, 0.f, 0.f};
    #pragma unroll
    for (int r = 0; r < 4; ++r) {
        const float* cr = cent + (size_t)idx[r] * DIM;
        #pragma unroll
        for (int i = 0; i < 12; ++i) dot[r] = fmaf(xv[i], cr[lane + i * 64], dot[r]);
    }
    #pragma unroll
    for (int r = 0; r < 4; ++r)
        #pragma unroll
        for (int off = 32; off; off >>= 1) dot[r] += __shfl_xor(dot[r], off, 64);
    ull best = ~0ull;
    #pragma unroll
    for (int r = 0; r < 4; ++r) {
        float sc = fmaf(-2.f, dot[r], nrm[idx[r]]);
        best = umin64(best, ((ull)fkey(sc) << 32) | (uint)idx[r]);  // ties -> lower idx
    }
    int cw = (int)(best & 0xFFFFFFFFull);
    if (lane == 0) cls[p] = cw;
    const float* cwr = cent + (size_t)cw * DIM;
    #pragma unroll
    for (int i = 0; i < 12; ++i) {
        int d = lane + i * 64;
        float nx = xv[i] - cwr[d];
        short h = f2bf(nx);
        xh[(size_t)p * DIM + d] = h;
        xl[(size_t)p * DIM + d] = f2bf(nx - bf2f(h));
    }
}

// ---------------- embed + diff outputs (LDS transpose, coalesced writes) ----------------
__global__ void embdiff_kernel(const short* __restrict__ xh, const short* __restrict__ xl,
    const int* __restrict__ cls0, const int* __restrict__ cls1, const int* __restrict__ cls2,
    const float* __restrict__ e0, const float* __restrict__ e1, const float* __restrict__ e2,
    float* __restrict__ out)
{
    __shared__ float s[196][65];
    int b = blockIdx.x / 12;
    int dc = (blockIdx.x % 12) * 64;
    int tid = threadIdx.x;
    int dl = tid & 63;
    // embed
    for (int it = 0; it < 49; ++it) {
        int pl = it * 4 + (tid >> 6);
        int p = b * 196 + pl;
        int d = dc + dl;
        s[pl][dl] = e0[(size_t)cls0[p] * DIM + d] + e1[(size_t)cls1[p] * DIM + d]
                  + e2[(size_t)cls2[p] * DIM + d];
    }
    __syncthreads();
    if (tid < 196) {
        for (int d = 0; d < 64; ++d)
            out[((size_t)b * DIM + dc + d) * 196 + tid] = s[tid][d];
    }
    __syncthreads();
    // diff (residual = xh + xl)
    for (int it = 0; it < 49; ++it) {
        int pl = it * 4 + (tid >> 6);
        size_t o = (size_t)(b * 196 + pl) * DIM + dc + dl;
        s[pl][dl] = bf2f(xh[o]) + bf2f(xl[o]);
    }
    __syncthreads();
    if (tid < 196) {
        float* od = out + 2 * (size_t)NP * DIM;
        for (int d = 0; d < 64; ++d)
            od[((size_t)b * DIM + dc + d) * 196 + tid] = s[tid][d];
    }
}

// ---------------- img_sum output ----------------
__global__ void img_kernel(
    const int* __restrict__ cls0, const int* __restrict__ cls1, const int* __restrict__ cls2,
    const float* __restrict__ c0, const float* __restrict__ c1, const float* __restrict__ c2,
    float* __restrict__ out)
{
    __shared__ float s[14][256];
    int bi = blockIdx.x;
    int b = bi / 42; int rem = bi % 42; int ch = rem / 14; int i = rem % 14;
    int tid = threadIdx.x;
    for (int j = 0; j < 14; ++j) {
        int p = b * 196 + i * 14 + j;
        int d = ch * 256 + tid;
        s[j][tid] = c0[(size_t)cls0[p] * DIM + d] + c1[(size_t)cls1[p] * DIM + d]
                  + c2[(size_t)cls2[p] * DIM + d];
    }
    __syncthreads();
    float* oi = out + (size_t)NP * DIM;
    if (tid < 224) {
        int j = tid >> 4, px = tid & 15;
        for (int py = 0; py < 16; ++py)
            oi[(((size_t)b * 3 + ch) * HWD + i * 16 + py) * HWD + tid] = s[j][py * 16 + px];
    }
}

extern "C" void kernel_launch(void* const* d_in, const int* in_sizes, int n_in,
                              void* d_out, int out_size, void* d_ws, size_t ws_size,
                              hipStream_t stream) {
    const float* data = (const float*)d_in[0];
    const float* c0 = (const float*)d_in[1];
    const float* c1 = (const float*)d_in[2];
    const float* c2 = (const float*)d_in[3];
    const float* e0 = (const float*)d_in[4];
    const float* e1 = (const float*)d_in[5];
    const float* e2 = (const float*)d_in[6];
    float* out = (float*)d_out;

    char* w = (char*)d_ws;
    short* xh = (short*)w;    w += (size_t)NP * DIM * 2;      // 9.63 MB
    short* xl = (short*)w;    w += (size_t)NP * DIM * 2;      // 9.63 MB
    short* chB = (short*)w;   w += (size_t)K2 * DIM * 2;      // 12.58 MB
    short* clB = (short*)w;   w += (size_t)K2 * DIM * 2;      // 12.58 MB
    float* nrm = (float*)w;   w += (size_t)K2 * 4;            // 32 KB
    ull* partB = (ull*)w;     w += (size_t)NP * 64 * 8;       // 3.21 MB
    ull* partS2 = (ull*)w;    w += (size_t)NP * 64 * 8;       // 3.21 MB
    int* cls0 = (int*)w;      w += (size_t)NP * 4;
    int* cls1 = (int*)w;      w += (size_t)NP * 4;
    int* cls2 = (int*)w;      w += (size_t)NP * 4;
    // total ~48.6 MiB

    patchify_split_kernel<<<(NP * DIM) / 256, 256, 0, stream>>>(data, xh, xl);

    // level 0: K=512, N/block=128 (NHT=4), grid (49,4) -> 8 partials (no swizzle: 196%8!=0)
    cprep_kernel<<<K0 / 4, 256, 0, stream>>>(c0, chB, clB, nrm);
    classify16<4><<<dim3(NP / 128, 4), 256, 0, stream>>>(xh, chB, clB, nrm, partB, partS2);
    merge_rescue_update<<<NP / 4, 256, 0, stream>>>(xh, xl, c0, nrm, partB, partS2, 8, cls0);

    // level 1: K=2048, N/block=256 (NHT=8), grid (49,8) -> 16 partials (swizzled)
    cprep_kernel<<<K1 / 4, 256, 0, stream>>>(c1, chB, clB, nrm);
    classify16<8><<<dim3(NP / 128, 8), 256, 0, stream>>>(xh, chB, clB, nrm, partB, partS2);
    merge_rescue_update<<<NP / 4, 256, 0, stream>>>(xh, xl, c1, nrm, partB, partS2, 16, cls1);

    // level 2: K=8192, N/block=256 (NHT=8), grid (49,32) -> 64 partials (swizzled)
    cprep_kernel<<<K2 / 4, 256, 0, stream>>>(c2, chB, clB, nrm);
    classify16<8><<<dim3(NP / 128, 32), 256, 0, stream>>>(xh, chB, clB, nrm, partB, partS2);
    merge_rescue_update<<<NP / 4, 256, 0, stream>>>(xh, xl, c2, nrm, partB, partS2, 64, cls2);

    embdiff_kernel<<<BATCH * 12, 256, 0, stream>>>(xh, xl, cls0, cls1, cls2, e0, e1, e2, out);
    img_kernel<<<BATCH * 3 * 14, 256, 0, stream>>>(cls0, cls1, cls2, c0, c1, c2, out);
}

// Round 5
// 564.354 us; speedup vs baseline: 1.0614x; 1.0103x over previous
//
#include <hip/hip_runtime.h>
#include <stdint.h>

#define BATCH 32
#define HWD 224
#define HP 14
#define NP (BATCH * HP * HP)   // 6272 patches = 49 * 128
#define DIM 768
#define K0 512
#define K1 2048
#define K2 8192

typedef unsigned long long ull;
typedef unsigned int uint;
typedef __attribute__((ext_vector_type(8))) short bf16x8;
typedef __attribute__((ext_vector_type(4))) float f32x4;

__device__ __forceinline__ uint fkey(float f) {
    uint u = __float_as_uint(f);
    return (u & 0x80000000u) ? ~u : (u | 0x80000000u);  // monotone fp32 -> u32
}
__device__ __forceinline__ short f2bf(float f) {       // round-to-nearest-even bf16
    uint u = __float_as_uint(f);
    uint r = (u + 0x7fffu + ((u >> 16) & 1u)) >> 16;
    return (short)r;
}
__device__ __forceinline__ float bf2f(short h) {
    return __uint_as_float(((uint)(unsigned short)h) << 16);
}
__device__ __forceinline__ ull umin64(ull a, ull b) { return a < b ? a : b; }
__device__ __forceinline__ ull umax64(ull a, ull b) { return a > b ? a : b; }

// ---------------- patchify + bf16 hi/lo split (residual kept as hi/lo pair) ----------------
__global__ void patchify_split_kernel(const float* __restrict__ data,
                                      short* __restrict__ xh, short* __restrict__ xl) {
    int gid = blockIdx.x * 256 + threadIdx.x;   // covers NP*DIM exactly
    int d = gid % DIM;
    int p = gid / DIM;
    int b = p / 196; int t = p % 196; int i = t / 14, j = t % 14;
    int ch = d >> 8; int r = d & 255; int py = r >> 4; int px = r & 15;
    float v = data[((b * 3 + ch) * HWD + i * 16 + py) * HWD + j * 16 + px];
    short h = f2bf(v);
    xh[gid] = h;
    xl[gid] = f2bf(v - bf2f(h));
}

// ---------------- center prep: bf16 hi/lo + row norms ----------------
__global__ void cprep_kernel(const float* __restrict__ c, short* __restrict__ ch,
                             short* __restrict__ cl, float* __restrict__ nrm) {
    int lane = threadIdx.x & 63;
    int row = blockIdx.x * 4 + (threadIdx.x >> 6);
    const float* src = c + (size_t)row * DIM;
    float s = 0.f;
    #pragma unroll
    for (int i = 0; i < 12; ++i) {
        int d = lane + i * 64;
        float v = src[d];
        short h = f2bf(v);
        ch[(size_t)row * DIM + d] = h;
        cl[(size_t)row * DIM + d] = f2bf(v - bf2f(h));
        s += v * v;
    }
    #pragma unroll
    for (int off = 32; off; off >>= 1) s += __shfl_xor(s, off, 64);
    if (lane == 0) nrm[row] = s;
}

// ---------------- MFMA classify (verified 16x16x32 layouts) ----------------
// 2-term split: x.c ~= xh.ch + xh.cl  (error = xl.c, top-2 partials + exact
// fp32 top-4 rescue in merge kernel absorbs it).
// Block 256 thr = 4 waves. Block tile M=128, N=128 (NHT=4). Wave tile 64m x 64n.
// LDS fragment-order layout + MFMA layouts: [measured: learn_hip m89-m97].
//
// R1: 2-phase prefetch.  R2/R4: XCD swizzle (FETCH -36%, time flat =>
// LATENCY-bound, not BW-bound; occupancy 19.8% == tail model).
// R5: 3-buffer pipeline with counted vmcnt across raw s_barrier (T3/T4).
//   - prefetch distance = 2 K-steps (was: compute-phase only; the
//     __syncthreads vmcnt(0) drain exposed staging latency every step).
//   - vmcnt(6): each stage = NJ=6 global_load_lds per wave; waiting "all but
//     newest batch" leaves next-next tile in flight across the barrier.
//   - NB=128 so 3 x 24 KB buffers fit at 2 blocks/CU (144 KB LDS, regs
//     ~164 unified -> still 2 waves/SIMD). Finer tiles also halve the
//     scheduler tail (3136 tiles / 512 slots).
__global__ __launch_bounds__(256, 2) void classify16(
    const short* __restrict__ xh,
    const short* __restrict__ chv, const short* __restrict__ clv,
    const float* __restrict__ nrm,
    ull* __restrict__ partB, ull* __restrict__ partS2)
{
    constexpr int NHT = 4;
    constexpr int NB = 128;                 // block N
    constexpr int CH0 = 512;                // ch slot base
    constexpr int CL0 = 512 + 128 * NHT;    // cl slot base (1024)
    constexpr int SLOTS = 512 + 256 * NHT;  // 1536 slots = 24 KB per buffer
    constexpr int NJ = 6;                   // staging instrs per wave
    constexpr int GX = NP / 128;            // 49 x-blocks
    __shared__ __align__(16) short lds[3 * SLOTS * 8];   // 72 KB (3-buffer)

    // T1 bijective XCD swizzle (gridY % 8 == 0 for L1/L2): each XCD owns a
    // contiguous by-chunk; its center slice (<=3.1 MB) stays L2-resident.
    int bx = blockIdx.x, by = blockIdx.y;
    if ((gridDim.y & 7) == 0) {
        int P = blockIdx.x + GX * blockIdx.y;
        int xcd = P & 7;
        int wofs = P >> 3;
        int ypx = gridDim.y >> 3;
        by = xcd * ypx + wofs / GX;
        bx = wofs % GX;
    }

    const int tid = threadIdx.x;
    const int lane = tid & 63;
    const int w = tid >> 6;
    const int wm = w & 1, wn = w >> 1;
    const int pbase = bx * 128;
    const int n0 = by * NB;

    // staging descriptors: group g covers slots [region + t*64, +64)
    const short* gp[NJ];
    int ls[NJ];
    #pragma unroll
    for (int j = 0; j < NJ; ++j) {
        int g = j * 4 + w;                  // 0..23: 8 xh, 8 ch, 8 cl groups
        const short* base; int rb, sb, t;
        if (g < 8)       { base = xh;  rb = pbase; sb = 0;    t = g; }
        else if (g < 16) { base = chv; rb = n0;    sb = CH0;  t = g - 8; }
        else             { base = clv; rb = n0;    sb = CL0;  t = g - 16; }
        gp[j] = base + (size_t)(rb + t * 16 + (lane & 15)) * DIM + ((lane >> 4) * 8);
        ls[j] = sb + t * 64;
    }

    f32x4 acc[4][NHT];
    #pragma unroll
    for (int i = 0; i < 4; ++i)
        #pragma unroll
        for (int u = 0; u < NHT; ++u) acc[i][u] = (f32x4){0.f, 0.f, 0.f, 0.f};

    auto stage = [&](int buf, int kt) {     // kt = K-tile index, dc = kt*32
        const int off = buf * SLOTS;
        #pragma unroll
        for (int j = 0; j < NJ; ++j) {
            __builtin_amdgcn_global_load_lds(
                (const __attribute__((address_space(1))) void*)(gp[j] + kt * 32),
                (__attribute__((address_space(3))) void*)(lds + (size_t)(off + ls[j]) * 8),
                16, 0, 0);
        }
    };
    auto compute = [&](int buf) {
        const bf16x8* Lc = (const bf16x8*)lds + buf * SLOTS;
        bf16x8 fxh[4];
        #pragma unroll
        for (int i = 0; i < 4; ++i)
            fxh[i] = Lc[(wm * 4 + i) * 64 + lane];
        #pragma unroll
        for (int u = 0; u < NHT; ++u) {
            bf16x8 fch = Lc[CH0 + (wn * NHT + u) * 64 + lane];
            bf16x8 fcl = Lc[CL0 + (wn * NHT + u) * 64 + lane];
            #pragma unroll
            for (int i = 0; i < 4; ++i) {
                acc[i][u] = __builtin_amdgcn_mfma_f32_16x16x32_bf16(fxh[i], fch, acc[i][u], 0, 0, 0);
                acc[i][u] = __builtin_amdgcn_mfma_f32_16x16x32_bf16(fxh[i], fcl, acc[i][u], 0, 0, 0);
            }
        }
    };

    // ---- 3-buffer pipelined K-loop: 24 K-tiles of 32 ----
    // prologue: tiles 0 and 1 issued; wait batch-0 done (6 newest in flight)
    stage(0, 0);
    stage(1, 1);
    asm volatile("s_waitcnt vmcnt(6)" ::: "memory");
    __builtin_amdgcn_s_barrier();
    __builtin_amdgcn_sched_barrier(0);

    #pragma unroll 3
    for (int t = 0; t < 24; ++t) {
        if (t + 2 < 24) stage((t + 2) % 3, t + 2);   // issue tile t+2
        compute(t % 3);                              // consume tile t
        if (t < 23) {
            // guarantee tile t+1's LDS writes landed; leave tile t+2 in flight
            if (t + 2 < 24) asm volatile("s_waitcnt vmcnt(6)" ::: "memory");
            else            asm volatile("s_waitcnt vmcnt(0)" ::: "memory");
            __builtin_amdgcn_s_barrier();
            __builtin_amdgcn_sched_barrier(0);
        }
    }

    // epilogue: per-row top-2 over this block's wave-half (64 centers)
    float nor[NHT]; uint ncol[NHT];
    #pragma unroll
    for (int u = 0; u < NHT; ++u) {
        ncol[u] = (uint)(n0 + (wn * NHT + u) * 16 + (lane & 15));
        nor[u] = nrm[ncol[u]];
    }
    const int pw = 2 * gridDim.y;           // partials per row
    #pragma unroll
    for (int i = 0; i < 4; ++i) {
        #pragma unroll
        for (int reg = 0; reg < 4; ++reg) {
            ull b = ~0ull, s2 = ~0ull;
            #pragma unroll
            for (int u = 0; u < NHT; ++u) {
                float s = fmaf(-2.f, acc[i][u][reg], nor[u]);
                ull pk = ((ull)fkey(s) << 32) | ncol[u];
                ull nb = umin64(b, pk);
                s2 = umin64(s2, umax64(b, pk));
                b = nb;
            }
            #pragma unroll
            for (int off = 1; off <= 8; off <<= 1) {   // reduce across lane&15
                ull ob = __shfl_xor(b, off, 64);
                ull os2 = __shfl_xor(s2, off, 64);
                ull nb = umin64(b, ob);
                s2 = umin64(umin64(s2, os2), umax64(b, ob));
                b = nb;
            }
            if ((lane & 15) == 0) {
                int row = pbase + (wm * 4 + i) * 16 + (lane >> 4) * 4 + reg;
                size_t o = (size_t)row * pw + (size_t)by * 2 + wn;
                partB[o] = b;
                partS2[o] = s2;
            }
        }
    }
}

// ---------------- merge partials + exact fp32 top-4 rescue + residual update ----------------
// nsplit = partials per row (stride); may exceed 64 -> strided merge loop.
__global__ void merge_rescue_update(
    short* __restrict__ xh, short* __restrict__ xl,
    const float* __restrict__ cent, const float* __restrict__ nrm,
    const ull* __restrict__ partB, const ull* __restrict__ partS2,
    int nsplit, int* __restrict__ cls)
{
    int lane = threadIdx.x & 63;
    int p = blockIdx.x * 4 + (threadIdx.x >> 6);
    ull a = ~0ull, c = ~0ull;
    for (int j = lane; j < nsplit; j += 64) {
        ull b2 = partB[(size_t)p * nsplit + j];
        ull s2b = partS2[(size_t)p * nsplit + j];
        ull na = umin64(a, b2);
        c = umin64(umin64(c, s2b), umax64(a, b2));
        a = na;
    }
    // extract top-4 candidates (packed keys unique: idx appears once)
    int idx[4];
    #pragma unroll
    for (int r = 0; r < 4; ++r) {
        ull m = a;
        #pragma unroll
        for (int off = 32; off; off >>= 1) m = umin64(m, __shfl_xor(m, off, 64));
        idx[r] = (int)(m & 0xFFFFFFFFull);
        if (a == m) { a = c; c = ~0ull; }   // pop from owning lane
    }
    // x reconstructed once into registers
    float xv[12];
    #pragma unroll
    for (int i = 0; i < 12; ++i) {
        int d = lane + i * 64;
        xv[i] = bf2f(xh[(size_t)p * DIM + d]) + bf2f(xl[(size_t)p * DIM + d]);
    }
    float dot[4] = {0.f, 0.f, 0.f, 0.f};
    #pragma unroll
    for (int r = 0; r < 4; ++r) {
        const float* cr = cent + (size_t)idx[r] * DIM;
        #pragma unroll
        for (int i = 0; i < 12; ++i) dot[r] = fmaf(xv[i], cr[lane + i * 64], dot[r]);
    }
    #pragma unroll
    for (int r = 0; r < 4; ++r)
        #pragma unroll
        for (int off = 32; off; off >>= 1) dot[r] += __shfl_xor(dot[r], off, 64);
    ull best = ~0ull;
    #pragma unroll
    for (int r = 0; r < 4; ++r) {
        float sc = fmaf(-2.f, dot[r], nrm[idx[r]]);
        best = umin64(best, ((ull)fkey(sc) << 32) | (uint)idx[r]);  // ties -> lower idx
    }
    int cw = (int)(best & 0xFFFFFFFFull);
    if (lane == 0) cls[p] = cw;
    const float* cwr = cent + (size_t)cw * DIM;
    #pragma unroll
    for (int i = 0; i < 12; ++i) {
        int d = lane + i * 64;
        float nx = xv[i] - cwr[d];
        short h = f2bf(nx);
        xh[(size_t)p * DIM + d] = h;
        xl[(size_t)p * DIM + d] = f2bf(nx - bf2f(h));
    }
}

// ---------------- embed + diff outputs (LDS transpose, coalesced writes) ----------------
__global__ void embdiff_kernel(const short* __restrict__ xh, const short* __restrict__ xl,
    const int* __restrict__ cls0, const int* __restrict__ cls1, const int* __restrict__ cls2,
    const float* __restrict__ e0, const float* __restrict__ e1, const float* __restrict__ e2,
    float* __restrict__ out)
{
    __shared__ float s[196][65];
    int b = blockIdx.x / 12;
    int dc = (blockIdx.x % 12) * 64;
    int tid = threadIdx.x;
    int dl = tid & 63;
    // embed
    for (int it = 0; it < 49; ++it) {
        int pl = it * 4 + (tid >> 6);
        int p = b * 196 + pl;
        int d = dc + dl;
        s[pl][dl] = e0[(size_t)cls0[p] * DIM + d] + e1[(size_t)cls1[p] * DIM + d]
                  + e2[(size_t)cls2[p] * DIM + d];
    }
    __syncthreads();
    if (tid < 196) {
        for (int d = 0; d < 64; ++d)
            out[((size_t)b * DIM + dc + d) * 196 + tid] = s[tid][d];
    }
    __syncthreads();
    // diff (residual = xh + xl)
    for (int it = 0; it < 49; ++it) {
        int pl = it * 4 + (tid >> 6);
        size_t o = (size_t)(b * 196 + pl) * DIM + dc + dl;
        s[pl][dl] = bf2f(xh[o]) + bf2f(xl[o]);
    }
    __syncthreads();
    if (tid < 196) {
        float* od = out + 2 * (size_t)NP * DIM;
        for (int d = 0; d < 64; ++d)
            od[((size_t)b * DIM + dc + d) * 196 + tid] = s[tid][d];
    }
}

// ---------------- img_sum output ----------------
__global__ void img_kernel(
    const int* __restrict__ cls0, const int* __restrict__ cls1, const int* __restrict__ cls2,
    const float* __restrict__ c0, const float* __restrict__ c1, const float* __restrict__ c2,
    float* __restrict__ out)
{
    __shared__ float s[14][256];
    int bi = blockIdx.x;
    int b = bi / 42; int rem = bi % 42; int ch = rem / 14; int i = rem % 14;
    int tid = threadIdx.x;
    for (int j = 0; j < 14; ++j) {
        int p = b * 196 + i * 14 + j;
        int d = ch * 256 + tid;
        s[j][tid] = c0[(size_t)cls0[p] * DIM + d] + c1[(size_t)cls1[p] * DIM + d]
                  + c2[(size_t)cls2[p] * DIM + d];
    }
    __syncthreads();
    float* oi = out + (size_t)NP * DIM;
    if (tid < 224) {
        int j = tid >> 4, px = tid & 15;
        for (int py = 0; py < 16; ++py)
            oi[(((size_t)b * 3 + ch) * HWD + i * 16 + py) * HWD + tid] = s[j][py * 16 + px];
    }
}

extern "C" void kernel_launch(void* const* d_in, const int* in_sizes, int n_in,
                              void* d_out, int out_size, void* d_ws, size_t ws_size,
                              hipStream_t stream) {
    const float* data = (const float*)d_in[0];
    const float* c0 = (const float*)d_in[1];
    const float* c1 = (const float*)d_in[2];
    const float* c2 = (const float*)d_in[3];
    const float* e0 = (const float*)d_in[4];
    const float* e1 = (const float*)d_in[5];
    const float* e2 = (const float*)d_in[6];
    float* out = (float*)d_out;

    char* w = (char*)d_ws;
    short* xh = (short*)w;    w += (size_t)NP * DIM * 2;      // 9.63 MB
    short* xl = (short*)w;    w += (size_t)NP * DIM * 2;      // 9.63 MB
    short* chB = (short*)w;   w += (size_t)K2 * DIM * 2;      // 12.58 MB
    short* clB = (short*)w;   w += (size_t)K2 * DIM * 2;      // 12.58 MB
    float* nrm = (float*)w;   w += (size_t)K2 * 4;            // 32 KB
    ull* partB = (ull*)w;     w += (size_t)NP * 128 * 8;      // 6.42 MB
    ull* partS2 = (ull*)w;    w += (size_t)NP * 128 * 8;      // 6.42 MB
    int* cls0 = (int*)w;      w += (size_t)NP * 4;
    int* cls1 = (int*)w;      w += (size_t)NP * 4;
    int* cls2 = (int*)w;      w += (size_t)NP * 4;
    // total ~57.5 MiB

    patchify_split_kernel<<<(NP * DIM) / 256, 256, 0, stream>>>(data, xh, xl);

    // level 0: K=512, NB=128 -> grid (49,4), 8 partials (no swizzle: 4%8!=0)
    cprep_kernel<<<K0 / 4, 256, 0, stream>>>(c0, chB, clB, nrm);
    classify16<<<dim3(NP / 128, K0 / 128), 256, 0, stream>>>(xh, chB, clB, nrm, partB, partS2);
    merge_rescue_update<<<NP / 4, 256, 0, stream>>>(xh, xl, c0, nrm, partB, partS2, 8, cls0);

    // level 1: K=2048, NB=128 -> grid (49,16), 32 partials (swizzled)
    cprep_kernel<<<K1 / 4, 256, 0, stream>>>(c1, chB, clB, nrm);
    classify16<<<dim3(NP / 128, K1 / 128), 256, 0, stream>>>(xh, chB, clB, nrm, partB, partS2);
    merge_rescue_update<<<NP / 4, 256, 0, stream>>>(xh, xl, c1, nrm, partB, partS2, 32, cls1);

    // level 2: K=8192, NB=128 -> grid (49,64), 128 partials (swizzled)
    cprep_kernel<<<K2 / 4, 256, 0, stream>>>(c2, chB, clB, nrm);
    classify16<<<dim3(NP / 128, K2 / 128), 256, 0, stream>>>(xh, chB, clB, nrm, partB, partS2);
    merge_rescue_update<<<NP / 4, 256, 0, stream>>>(xh, xl, c2, nrm, partB, partS2, 128, cls2);

    embdiff_kernel<<<BATCH * 12, 256, 0, stream>>>(xh, xl, cls0, cls1, cls2, e0, e1, e2, out);
    img_kernel<<<BATCH * 3 * 14, 256, 0, stream>>>(cls0, cls1, cls2, c0, c1, c2, out);
}

// Round 7
// 460.671 us; speedup vs baseline: 1.3002x; 1.2251x over previous
//
#include <hip/hip_runtime.h>
#include <stdint.h>

#define BATCH 32
#define HWD 224
#define HP 14
#define NP (BATCH * HP * HP)   // 6272 patches = 49 * 128
#define DIM 768
#define K0 512
#define K1 2048
#define K2 8192

typedef unsigned long long ull;
typedef unsigned int uint;
typedef __attribute__((ext_vector_type(8))) short bf16x8;
typedef __attribute__((ext_vector_type(4))) float f32x4;

__device__ __forceinline__ uint fkey(float f) {
    uint u = __float_as_uint(f);
    return (u & 0x80000000u) ? ~u : (u | 0x80000000u);  // monotone fp32 -> u32
}
__device__ __forceinline__ short f2bf(float f) {       // round-to-nearest-even bf16
    uint u = __float_as_uint(f);
    uint r = (u + 0x7fffu + ((u >> 16) & 1u)) >> 16;
    return (short)r;
}
__device__ __forceinline__ float bf2f(short h) {
    return __uint_as_float(((uint)(unsigned short)h) << 16);
}
__device__ __forceinline__ ull umin64(ull a, ull b) { return a < b ? a : b; }
__device__ __forceinline__ ull umax64(ull a, ull b) { return a > b ? a : b; }

// ---------------- patchify + bf16 hi/lo split (residual kept as hi/lo pair) ----------------
// xl still needed: merge reconstructs exact x = xh + xl, and diff output uses it.
__global__ void patchify_split_kernel(const float* __restrict__ data,
                                      short* __restrict__ xh, short* __restrict__ xl) {
    int gid = blockIdx.x * 256 + threadIdx.x;   // covers NP*DIM exactly
    int d = gid % DIM;
    int p = gid / DIM;
    int b = p / 196; int t = p % 196; int i = t / 14, j = t % 14;
    int ch = d >> 8; int r = d & 255; int py = r >> 4; int px = r & 15;
    float v = data[((b * 3 + ch) * HWD + i * 16 + py) * HWD + j * 16 + px];
    short h = f2bf(v);
    xh[gid] = h;
    xl[gid] = f2bf(v - bf2f(h));
}

// ---------------- center prep: bf16 hi + exact fp32 row norms ----------------
// R6: cl dropped -- classify is now single-term xh.ch (see classify16 comment).
__global__ void cprep_kernel(const float* __restrict__ c, short* __restrict__ ch,
                             float* __restrict__ nrm) {
    int lane = threadIdx.x & 63;
    int row = blockIdx.x * 4 + (threadIdx.x >> 6);
    const float* src = c + (size_t)row * DIM;
    float s = 0.f;
    #pragma unroll
    for (int i = 0; i < 12; ++i) {
        int d = lane + i * 64;
        float v = src[d];
        ch[(size_t)row * DIM + d] = f2bf(v);
        s += v * v;
    }
    #pragma unroll
    for (int off = 32; off; off >>= 1) s += __shfl_xor(s, off, 64);
    if (lane == 0) nrm[row] = s;
}

// ---------------- MFMA classify (verified 16x16x32 layouts) ----------------
// R6: SINGLE-TERM score: x.c ~= xh.ch. The old 2-term split (xh.ch + xh.cl)
// already dropped xl.c (sigma ~0.02-0.03 on the dot); dropping xh.cl adds a
// statistically identical term (total ~0.06). Min-gaps among 8192 Gaussian
// centers are O(10) and the merge kernel re-scores top-4 candidates in exact
// fp32 -- misclassification probability is negligible. This HALVES classify
// MFMA work, cuts staging 6->4 loads and LDS 24->16 KB/buffer, which unlocks
// 3 blocks/CU (3 x 48 KB = 144 KB LDS, ~144 unified regs < 170).
// Evidence for the change: R0-R5 pinned MfmaUtil at 26-27% across four
// pipeline structures -- work volume, not schedule, is the lever.
//
// Block 256 thr = 4 waves. Block tile M=128, N=128. Wave tile 64m x 64n.
// LDS fragment-order layout + MFMA layouts: [measured: learn_hip m89-m97].
// Pipeline (R5, kept): 3-buffer, prefetch distance 2, counted vmcnt across
// raw s_barrier. vmcnt(4): each stage = NJ=4 global_load_lds per wave;
// waiting "all but newest batch" leaves the next-next tile in flight.
// XCD swizzle (R2, kept): each XCD owns a contiguous by-chunk -> its center
// slice stays L2-resident (FETCH -36% measured). Identity when gridY%8 != 0.
__global__ __launch_bounds__(256, 3) void classify16(
    const short* __restrict__ xh,
    const short* __restrict__ chv,
    const float* __restrict__ nrm,
    ull* __restrict__ partB, ull* __restrict__ partS2)
{
    constexpr int NHT = 4;
    constexpr int NB = 128;                 // block N
    constexpr int CH0 = 512;                // ch slot base
    constexpr int SLOTS = 1024;             // 16 KB per buffer
    constexpr int NJ = 4;                   // staging instrs per wave
    constexpr int GX = NP / 128;            // 49 x-blocks
    __shared__ __align__(16) short lds[3 * SLOTS * 8];   // 48 KB (3-buffer)

    int bx = blockIdx.x, by = blockIdx.y;
    if ((gridDim.y & 7) == 0) {
        int P = blockIdx.x + GX * blockIdx.y;
        int xcd = P & 7;
        int wofs = P >> 3;
        int ypx = gridDim.y >> 3;
        by = xcd * ypx + wofs / GX;
        bx = wofs % GX;
    }

    const int tid = threadIdx.x;
    const int lane = tid & 63;
    const int w = tid >> 6;
    const int wm = w & 1, wn = w >> 1;
    const int pbase = bx * 128;
    const int n0 = by * NB;

    // staging descriptors: group g covers slots [region + t*64, +64)
    const short* gp[NJ];
    int ls[NJ];
    #pragma unroll
    for (int j = 0; j < NJ; ++j) {
        int g = j * 4 + w;                  // 0..15: 8 xh groups, 8 ch groups
        const short* base; int rb, sb, t;
        if (g < 8) { base = xh;  rb = pbase; sb = 0;    t = g; }
        else       { base = chv; rb = n0;    sb = CH0;  t = g - 8; }
        gp[j] = base + (size_t)(rb + t * 16 + (lane & 15)) * DIM + ((lane >> 4) * 8);
        ls[j] = sb + t * 64;
    }

    f32x4 acc[4][NHT];
    #pragma unroll
    for (int i = 0; i < 4; ++i)
        #pragma unroll
        for (int u = 0; u < NHT; ++u) acc[i][u] = (f32x4){0.f, 0.f, 0.f, 0.f};

    auto stage = [&](int buf, int kt) {     // kt = K-tile index, dc = kt*32
        const int off = buf * SLOTS;
        #pragma unroll
        for (int j = 0; j < NJ; ++j) {
            __builtin_amdgcn_global_load_lds(
                (const __attribute__((address_space(1))) void*)(gp[j] + kt * 32),
                (__attribute__((address_space(3))) void*)(lds + (size_t)(off + ls[j]) * 8),
                16, 0, 0);
        }
    };
    auto compute = [&](int buf) {
        const bf16x8* Lc = (const bf16x8*)lds + buf * SLOTS;
        bf16x8 fxh[4];
        #pragma unroll
        for (int i = 0; i < 4; ++i)
            fxh[i] = Lc[(wm * 4 + i) * 64 + lane];
        #pragma unroll
        for (int u = 0; u < NHT; ++u) {
            bf16x8 fch = Lc[CH0 + (wn * NHT + u) * 64 + lane];
            #pragma unroll
            for (int i = 0; i < 4; ++i)
                acc[i][u] = __builtin_amdgcn_mfma_f32_16x16x32_bf16(fxh[i], fch, acc[i][u], 0, 0, 0);
        }
    };

    // ---- 3-buffer pipelined K-loop: 24 K-tiles of 32 ----
    stage(0, 0);
    stage(1, 1);
    asm volatile("s_waitcnt vmcnt(4)" ::: "memory");   // tile 0 landed
    __builtin_amdgcn_s_barrier();
    __builtin_amdgcn_sched_barrier(0);

    #pragma unroll 3
    for (int t = 0; t < 24; ++t) {
        if (t + 2 < 24) stage((t + 2) % 3, t + 2);   // issue tile t+2
        compute(t % 3);                              // consume tile t
        if (t < 23) {
            // guarantee tile t+1's LDS writes landed; leave tile t+2 in flight
            if (t + 2 < 24) asm volatile("s_waitcnt vmcnt(4)" ::: "memory");
            else            asm volatile("s_waitcnt vmcnt(0)" ::: "memory");
            __builtin_amdgcn_s_barrier();
            __builtin_amdgcn_sched_barrier(0);
        }
    }

    // epilogue: per-row top-2 over this block's wave-half (64 centers)
    float nor[NHT]; uint ncol[NHT];
    #pragma unroll
    for (int u = 0; u < NHT; ++u) {
        ncol[u] = (uint)(n0 + (wn * NHT + u) * 16 + (lane & 15));
        nor[u] = nrm[ncol[u]];
    }
    const int pw = 2 * gridDim.y;           // partials per row
    #pragma unroll
    for (int i = 0; i < 4; ++i) {
        #pragma unroll
        for (int reg = 0; reg < 4; ++reg) {
            ull b = ~0ull, s2 = ~0ull;
            #pragma unroll
            for (int u = 0; u < NHT; ++u) {
                float s = fmaf(-2.f, acc[i][u][reg], nor[u]);
                ull pk = ((ull)fkey(s) << 32) | ncol[u];
                ull nb = umin64(b, pk);
                s2 = umin64(s2, umax64(b, pk));
                b = nb;
            }
            #pragma unroll
            for (int off = 1; off <= 8; off <<= 1) {   // reduce across lane&15
                ull ob = __shfl_xor(b, off, 64);
                ull os2 = __shfl_xor(s2, off, 64);
                ull nb = umin64(b, ob);
                s2 = umin64(umin64(s2, os2), umax64(b, ob));
                b = nb;
            }
            if ((lane & 15) == 0) {
                int row = pbase + (wm * 4 + i) * 16 + (lane >> 4) * 4 + reg;
                size_t o = (size_t)row * pw + (size_t)by * 2 + wn;
                partB[o] = b;
                partS2[o] = s2;
            }
        }
    }
}

// ---------------- merge partials + exact fp32 top-4 rescue + residual update ----------------
// nsplit = partials per row (stride); may exceed 64 -> strided merge loop.
__global__ void merge_rescue_update(
    short* __restrict__ xh, short* __restrict__ xl,
    const float* __restrict__ cent, const float* __restrict__ nrm,
    const ull* __restrict__ partB, const ull* __restrict__ partS2,
    int nsplit, int* __restrict__ cls)
{
    int lane = threadIdx.x & 63;
    int p = blockIdx.x * 4 + (threadIdx.x >> 6);
    ull a = ~0ull, c = ~0ull;
    for (int j = lane; j < nsplit; j += 64) {
        ull b2 = partB[(size_t)p * nsplit + j];
        ull s2b = partS2[(size_t)p * nsplit + j];
        ull na = umin64(a, b2);
        c = umin64(umin64(c, s2b), umax64(a, b2));
        a = na;
    }
    // extract top-4 candidates (packed keys unique: idx appears once)
    int idx[4];
    #pragma unroll
    for (int r = 0; r < 4; ++r) {
        ull m = a;
        #pragma unroll
        for (int off = 32; off; off >>= 1) m = umin64(m, __shfl_xor(m, off, 64));
        idx[r] = (int)(m & 0xFFFFFFFFull);
        if (a == m) { a = c; c = ~0ull; }   // pop from owning lane
    }
    // x reconstructed once into registers
    float xv[12];
    #pragma unroll
    for (int i = 0; i < 12; ++i) {
        int d = lane + i * 64;
        xv[i] = bf2f(xh[(size_t)p * DIM + d]) + bf2f(xl[(size_t)p * DIM + d]);
    }
    float dot[4] = {0.f, 0.f, 0.f, 0.f};
    #pragma unroll
    for (int r = 0; r < 4; ++r) {
        const float* cr = cent + (size_t)idx[r] * DIM;
        #pragma unroll
        for (int i = 0; i < 12; ++i) dot[r] = fmaf(xv[i], cr[lane + i * 64], dot[r]);
    }
    #pragma unroll
    for (int r = 0; r < 4; ++r)
        #pragma unroll
        for (int off = 32; off; off >>= 1) dot[r] += __shfl_xor(dot[r], off, 64);
    ull best = ~0ull;
    #pragma unroll
    for (int r = 0; r < 4; ++r) {
        float sc = fmaf(-2.f, dot[r], nrm[idx[r]]);
        best = umin64(best, ((ull)fkey(sc) << 32) | (uint)idx[r]);  // ties -> lower idx
    }
    int cw = (int)(best & 0xFFFFFFFFull);
    if (lane == 0) cls[p] = cw;
    const float* cwr = cent + (size_t)cw * DIM;
    #pragma unroll
    for (int i = 0; i < 12; ++i) {
        int d = lane + i * 64;
        float nx = xv[i] - cwr[d];
        short h = f2bf(nx);
        xh[(size_t)p * DIM + d] = h;
        xl[(size_t)p * DIM + d] = f2bf(nx - bf2f(h));
    }
}

// ---------------- embed + diff outputs (LDS transpose, coalesced writes) ----------------
__global__ void embdiff_kernel(const short* __restrict__ xh, const short* __restrict__ xl,
    const int* __restrict__ cls0, const int* __restrict__ cls1, const int* __restrict__ cls2,
    const float* __restrict__ e0, const float* __restrict__ e1, const float* __restrict__ e2,
    float* __restrict__ out)
{
    __shared__ float s[196][65];
    int b = blockIdx.x / 12;
    int dc = (blockIdx.x % 12) * 64;
    int tid = threadIdx.x;
    int dl = tid & 63;
    // embed
    for (int it = 0; it < 49; ++it) {
        int pl = it * 4 + (tid >> 6);
        int p = b * 196 + pl;
        int d = dc + dl;
        s[pl][dl] = e0[(size_t)cls0[p] * DIM + d] + e1[(size_t)cls1[p] * DIM + d]
                  + e2[(size_t)cls2[p] * DIM + d];
    }
    __syncthreads();
    if (tid < 196) {
        for (int d = 0; d < 64; ++d)
            out[((size_t)b * DIM + dc + d) * 196 + tid] = s[tid][d];
    }
    __syncthreads();
    // diff (residual = xh + xl)
    for (int it = 0; it < 49; ++it) {
        int pl = it * 4 + (tid >> 6);
        size_t o = (size_t)(b * 196 + pl) * DIM + dc + dl;
        s[pl][dl] = bf2f(xh[o]) + bf2f(xl[o]);
    }
    __syncthreads();
    if (tid < 196) {
        float* od = out + 2 * (size_t)NP * DIM;
        for (int d = 0; d < 64; ++d)
            od[((size_t)b * DIM + dc + d) * 196 + tid] = s[tid][d];
    }
}

// ---------------- img_sum output ----------------
__global__ void img_kernel(
    const int* __restrict__ cls0, const int* __restrict__ cls1, const int* __restrict__ cls2,
    const float* __restrict__ c0, const float* __restrict__ c1, const float* __restrict__ c2,
    float* __restrict__ out)
{
    __shared__ float s[14][256];
    int bi = blockIdx.x;
    int b = bi / 42; int rem = bi % 42; int ch = rem / 14; int i = rem % 14;
    int tid = threadIdx.x;
    for (int j = 0; j < 14; ++j) {
        int p = b * 196 + i * 14 + j;
        int d = ch * 256 + tid;
        s[j][tid] = c0[(size_t)cls0[p] * DIM + d] + c1[(size_t)cls1[p] * DIM + d]
                  + c2[(size_t)cls2[p] * DIM + d];
    }
    __syncthreads();
    float* oi = out + (size_t)NP * DIM;
    if (tid < 224) {
        int j = tid >> 4, px = tid & 15;
        for (int py = 0; py < 16; ++py)
            oi[(((size_t)b * 3 + ch) * HWD + i * 16 + py) * HWD + tid] = s[j][py * 16 + px];
    }
}

extern "C" void kernel_launch(void* const* d_in, const int* in_sizes, int n_in,
                              void* d_out, int out_size, void* d_ws, size_t ws_size,
                              hipStream_t stream) {
    const float* data = (const float*)d_in[0];
    const float* c0 = (const float*)d_in[1];
    const float* c1 = (const float*)d_in[2];
    const float* c2 = (const float*)d_in[3];
    const float* e0 = (const float*)d_in[4];
    const float* e1 = (const float*)d_in[5];
    const float* e2 = (const float*)d_in[6];
    float* out = (float*)d_out;

    char* w = (char*)d_ws;
    short* xh = (short*)w;    w += (size_t)NP * DIM * 2;      // 9.63 MB
    short* xl = (short*)w;    w += (size_t)NP * DIM * 2;      // 9.63 MB
    short* chB = (short*)w;   w += (size_t)K2 * DIM * 2;      // 12.58 MB
    float* nrm = (float*)w;   w += (size_t)K2 * 4;            // 32 KB
    ull* partB = (ull*)w;     w += (size_t)NP * 128 * 8;      // 6.42 MB
    ull* partS2 = (ull*)w;    w += (size_t)NP * 128 * 8;      // 6.42 MB
    int* cls0 = (int*)w;      w += (size_t)NP * 4;
    int* cls1 = (int*)w;      w += (size_t)NP * 4;
    int* cls2 = (int*)w;      w += (size_t)NP * 4;
    // total ~44.9 MiB

    patchify_split_kernel<<<(NP * DIM) / 256, 256, 0, stream>>>(data, xh, xl);

    // level 0: K=512, NB=128 -> grid (49,4), 8 partials (no swizzle: 4%8!=0)
    cprep_kernel<<<K0 / 4, 256, 0, stream>>>(c0, chB, nrm);
    classify16<<<dim3(NP / 128, K0 / 128), 256, 0, stream>>>(xh, chB, nrm, partB, partS2);
    merge_rescue_update<<<NP / 4, 256, 0, stream>>>(xh, xl, c0, nrm, partB, partS2, 8, cls0);

    // level 1: K=2048, NB=128 -> grid (49,16), 32 partials (swizzled)
    cprep_kernel<<<K1 / 4, 256, 0, stream>>>(c1, chB, nrm);
    classify16<<<dim3(NP / 128, K1 / 128), 256, 0, stream>>>(xh, chB, nrm, partB, partS2);
    merge_rescue_update<<<NP / 4, 256, 0, stream>>>(xh, xl, c1, nrm, partB, partS2, 32, cls1);

    // level 2: K=8192, NB=128 -> grid (49,64), 128 partials (swizzled)
    cprep_kernel<<<K2 / 4, 256, 0, stream>>>(c2, chB, nrm);
    classify16<<<dim3(NP / 128, K2 / 128), 256, 0, stream>>>(xh, chB, nrm, partB, partS2);
    merge_rescue_update<<<NP / 4, 256, 0, stream>>>(xh, xl, c2, nrm, partB, partS2, 128, cls2);

    embdiff_kernel<<<BATCH * 12, 256, 0, stream>>>(xh, xl, cls0, cls1, cls2, e0, e1, e2, out);
    img_kernel<<<BATCH * 3 * 14, 256, 0, stream>>>(cls0, cls1, cls2, c0, c1, c2, out);
}

// Round 8
// 458.739 us; speedup vs baseline: 1.3057x; 1.0042x over previous
//
#include <hip/hip_runtime.h>
#include <stdint.h>

#define BATCH 32
#define HWD 224
#define HP 14
#define NP (BATCH * HP * HP)   // 6272 patches = 49 * 128
#define DIM 768
#define K0 512
#define K1 2048
#define K2 8192

typedef unsigned long long ull;
typedef unsigned int uint;
typedef __attribute__((ext_vector_type(8))) short bf16x8;
typedef __attribute__((ext_vector_type(4))) float f32x4;

__device__ __forceinline__ uint fkey(float f) {
    uint u = __float_as_uint(f);
    return (u & 0x80000000u) ? ~u : (u | 0x80000000u);  // monotone fp32 -> u32
}
__device__ __forceinline__ short f2bf(float f) {       // round-to-nearest-even bf16
    uint u = __float_as_uint(f);
    uint r = (u + 0x7fffu + ((u >> 16) & 1u)) >> 16;
    return (short)r;
}
__device__ __forceinline__ float bf2f(short h) {
    return __uint_as_float(((uint)(unsigned short)h) << 16);
}
__device__ __forceinline__ ull umin64(ull a, ull b) { return a < b ? a : b; }
__device__ __forceinline__ ull umax64(ull a, ull b) { return a > b ? a : b; }

// ---------------- patchify + bf16 hi/lo split (residual kept as hi/lo pair) ----------------
// xl still needed: merge reconstructs exact x = xh + xl, and diff output uses it.
__global__ void patchify_split_kernel(const float* __restrict__ data,
                                      short* __restrict__ xh, short* __restrict__ xl) {
    int gid = blockIdx.x * 256 + threadIdx.x;   // covers NP*DIM exactly
    int d = gid % DIM;
    int p = gid / DIM;
    int b = p / 196; int t = p % 196; int i = t / 14, j = t % 14;
    int ch = d >> 8; int r = d & 255; int py = r >> 4; int px = r & 15;
    float v = data[((b * 3 + ch) * HWD + i * 16 + py) * HWD + j * 16 + px];
    short h = f2bf(v);
    xh[gid] = h;
    xl[gid] = f2bf(v - bf2f(h));
}

// ---------------- center prep: bf16 hi + exact fp32 row norms ----------------
__global__ void cprep_kernel(const float* __restrict__ c, short* __restrict__ ch,
                             float* __restrict__ nrm) {
    int lane = threadIdx.x & 63;
    int row = blockIdx.x * 4 + (threadIdx.x >> 6);
    const float* src = c + (size_t)row * DIM;
    float s = 0.f;
    #pragma unroll
    for (int i = 0; i < 12; ++i) {
        int d = lane + i * 64;
        float v = src[d];
        ch[(size_t)row * DIM + d] = f2bf(v);
        s += v * v;
    }
    #pragma unroll
    for (int off = 32; off; off >>= 1) s += __shfl_xor(s, off, 64);
    if (lane == 0) nrm[row] = s;
}

// ---------------- MFMA classify (verified 16x16x32 layouts) ----------------
// R6: single-term score xh.ch (top-2 partials + exact fp32 top-4 rescue absorb
// the ~0.06-sigma bf16 truncation noise; min-gaps are O(10)).
// R7 evidence: per-block K-step time was 4200 cyc in BOTH R5 (2-term) and R7
// (1-term) -- halving MFMA+LDS+staging changed step time ZERO; the win was
// pure occupancy. => steps are pinned by L2-MISS LATENCY (xh re-streamed:
// bx-fast order pushes 77 MB/XCD through a 4 MB L2; ~256 miss-lines/step
// cannot be covered by any prefetch depth).
// R8: flip intra-XCD sweep to BY-FAST, BX-SLOW. Same by-band partition per
// XCD (centers band 1.58 MB L2-resident), but now each bx's xh chunk
// (196 KB) is reused across the band's ypx by-values before moving on ->
// steady-state staging loads are L2 HITS (~200 cyc, hidden by depth-2
// prefetch). Per-XCD compulsory misses 77 -> ~11 MB.
// Pipeline (R5): 3-buffer, prefetch distance 2, counted vmcnt across raw
// s_barrier; vmcnt(4) leaves the newest stage batch in flight.
__global__ __launch_bounds__(256, 3) void classify16(
    const short* __restrict__ xh,
    const short* __restrict__ chv,
    const float* __restrict__ nrm,
    ull* __restrict__ partB, ull* __restrict__ partS2)
{
    constexpr int NHT = 4;
    constexpr int NB = 128;                 // block N
    constexpr int CH0 = 512;                // ch slot base
    constexpr int SLOTS = 1024;             // 16 KB per buffer
    constexpr int NJ = 4;                   // staging instrs per wave
    constexpr int GX = NP / 128;            // 49 x-blocks
    __shared__ __align__(16) short lds[3 * SLOTS * 8];   // 48 KB (3-buffer)

    // R8 swizzle: xcd owns by-band [xcd*ypx, +ypx); within the XCD, by varies
    // FASTEST (xh chunk reuse), bx slowest. Bijective: GX*GY/8 = GX*ypx.
    int bx = blockIdx.x, by = blockIdx.y;
    if ((gridDim.y & 7) == 0) {
        int P = blockIdx.x + GX * blockIdx.y;
        int xcd = P & 7;
        int wofs = P >> 3;                  // 0 .. GX*ypx - 1
        int ypx = gridDim.y >> 3;           // by-values per XCD
        by = xcd * ypx + (wofs % ypx);
        bx = wofs / ypx;
    }

    const int tid = threadIdx.x;
    const int lane = tid & 63;
    const int w = tid >> 6;
    const int wm = w & 1, wn = w >> 1;
    const int pbase = bx * 128;
    const int n0 = by * NB;

    // staging descriptors: group g covers slots [region + t*64, +64)
    const short* gp[NJ];
    int ls[NJ];
    #pragma unroll
    for (int j = 0; j < NJ; ++j) {
        int g = j * 4 + w;                  // 0..15: 8 xh groups, 8 ch groups
        const short* base; int rb, sb, t;
        if (g < 8) { base = xh;  rb = pbase; sb = 0;    t = g; }
        else       { base = chv; rb = n0;    sb = CH0;  t = g - 8; }
        gp[j] = base + (size_t)(rb + t * 16 + (lane & 15)) * DIM + ((lane >> 4) * 8);
        ls[j] = sb + t * 64;
    }

    f32x4 acc[4][NHT];
    #pragma unroll
    for (int i = 0; i < 4; ++i)
        #pragma unroll
        for (int u = 0; u < NHT; ++u) acc[i][u] = (f32x4){0.f, 0.f, 0.f, 0.f};

    auto stage = [&](int buf, int kt) {     // kt = K-tile index, dc = kt*32
        const int off = buf * SLOTS;
        #pragma unroll
        for (int j = 0; j < NJ; ++j) {
            __builtin_amdgcn_global_load_lds(
                (const __attribute__((address_space(1))) void*)(gp[j] + kt * 32),
                (__attribute__((address_space(3))) void*)(lds + (size_t)(off + ls[j]) * 8),
                16, 0, 0);
        }
    };
    auto compute = [&](int buf) {
        const bf16x8* Lc = (const bf16x8*)lds + buf * SLOTS;
        bf16x8 fxh[4];
        #pragma unroll
        for (int i = 0; i < 4; ++i)
            fxh[i] = Lc[(wm * 4 + i) * 64 + lane];
        #pragma unroll
        for (int u = 0; u < NHT; ++u) {
            bf16x8 fch = Lc[CH0 + (wn * NHT + u) * 64 + lane];
            #pragma unroll
            for (int i = 0; i < 4; ++i)
                acc[i][u] = __builtin_amdgcn_mfma_f32_16x16x32_bf16(fxh[i], fch, acc[i][u], 0, 0, 0);
        }
    };

    // ---- 3-buffer pipelined K-loop: 24 K-tiles of 32 ----
    stage(0, 0);
    stage(1, 1);
    asm volatile("s_waitcnt vmcnt(4)" ::: "memory");   // tile 0 landed
    __builtin_amdgcn_s_barrier();
    __builtin_amdgcn_sched_barrier(0);

    #pragma unroll 3
    for (int t = 0; t < 24; ++t) {
        if (t + 2 < 24) stage((t + 2) % 3, t + 2);   // issue tile t+2
        compute(t % 3);                              // consume tile t
        if (t < 23) {
            // guarantee tile t+1's LDS writes landed; leave tile t+2 in flight
            if (t + 2 < 24) asm volatile("s_waitcnt vmcnt(4)" ::: "memory");
            else            asm volatile("s_waitcnt vmcnt(0)" ::: "memory");
            __builtin_amdgcn_s_barrier();
            __builtin_amdgcn_sched_barrier(0);
        }
    }

    // epilogue: per-row top-2 over this block's wave-half (64 centers)
    float nor[NHT]; uint ncol[NHT];
    #pragma unroll
    for (int u = 0; u < NHT; ++u) {
        ncol[u] = (uint)(n0 + (wn * NHT + u) * 16 + (lane & 15));
        nor[u] = nrm[ncol[u]];
    }
    const int pw = 2 * gridDim.y;           // partials per row
    #pragma unroll
    for (int i = 0; i < 4; ++i) {
        #pragma unroll
        for (int reg = 0; reg < 4; ++reg) {
            ull b = ~0ull, s2 = ~0ull;
            #pragma unroll
            for (int u = 0; u < NHT; ++u) {
                float s = fmaf(-2.f, acc[i][u][reg], nor[u]);
                ull pk = ((ull)fkey(s) << 32) | ncol[u];
                ull nb = umin64(b, pk);
                s2 = umin64(s2, umax64(b, pk));
                b = nb;
            }
            #pragma unroll
            for (int off = 1; off <= 8; off <<= 1) {   // reduce across lane&15
                ull ob = __shfl_xor(b, off, 64);
                ull os2 = __shfl_xor(s2, off, 64);
                ull nb = umin64(b, ob);
                s2 = umin64(umin64(s2, os2), umax64(b, ob));
                b = nb;
            }
            if ((lane & 15) == 0) {
                int row = pbase + (wm * 4 + i) * 16 + (lane >> 4) * 4 + reg;
                size_t o = (size_t)row * pw + (size_t)by * 2 + wn;
                partB[o] = b;
                partS2[o] = s2;
            }
        }
    }
}

// ---------------- merge partials + exact fp32 top-4 rescue + residual update ----------------
// nsplit = partials per row (stride); may exceed 64 -> strided merge loop.
__global__ void merge_rescue_update(
    short* __restrict__ xh, short* __restrict__ xl,
    const float* __restrict__ cent, const float* __restrict__ nrm,
    const ull* __restrict__ partB, const ull* __restrict__ partS2,
    int nsplit, int* __restrict__ cls)
{
    int lane = threadIdx.x & 63;
    int p = blockIdx.x * 4 + (threadIdx.x >> 6);
    ull a = ~0ull, c = ~0ull;
    for (int j = lane; j < nsplit; j += 64) {
        ull b2 = partB[(size_t)p * nsplit + j];
        ull s2b = partS2[(size_t)p * nsplit + j];
        ull na = umin64(a, b2);
        c = umin64(umin64(c, s2b), umax64(a, b2));
        a = na;
    }
    // extract top-4 candidates (packed keys unique: idx appears once)
    int idx[4];
    #pragma unroll
    for (int r = 0; r < 4; ++r) {
        ull m = a;
        #pragma unroll
        for (int off = 32; off; off >>= 1) m = umin64(m, __shfl_xor(m, off, 64));
        idx[r] = (int)(m & 0xFFFFFFFFull);
        if (a == m) { a = c; c = ~0ull; }   // pop from owning lane
    }
    // x reconstructed once into registers
    float xv[12];
    #pragma unroll
    for (int i = 0; i < 12; ++i) {
        int d = lane + i * 64;
        xv[i] = bf2f(xh[(size_t)p * DIM + d]) + bf2f(xl[(size_t)p * DIM + d]);
    }
    float dot[4] = {0.f, 0.f, 0.f, 0.f};
    #pragma unroll
    for (int r = 0; r < 4; ++r) {
        const float* cr = cent + (size_t)idx[r] * DIM;
        #pragma unroll
        for (int i = 0; i < 12; ++i) dot[r] = fmaf(xv[i], cr[lane + i * 64], dot[r]);
    }
    #pragma unroll
    for (int r = 0; r < 4; ++r)
        #pragma unroll
        for (int off = 32; off; off >>= 1) dot[r] += __shfl_xor(dot[r], off, 64);
    ull best = ~0ull;
    #pragma unroll
    for (int r = 0; r < 4; ++r) {
        float sc = fmaf(-2.f, dot[r], nrm[idx[r]]);
        best = umin64(best, ((ull)fkey(sc) << 32) | (uint)idx[r]);  // ties -> lower idx
    }
    int cw = (int)(best & 0xFFFFFFFFull);
    if (lane == 0) cls[p] = cw;
    const float* cwr = cent + (size_t)cw * DIM;
    #pragma unroll
    for (int i = 0; i < 12; ++i) {
        int d = lane + i * 64;
        float nx = xv[i] - cwr[d];
        short h = f2bf(nx);
        xh[(size_t)p * DIM + d] = h;
        xl[(size_t)p * DIM + d] = f2bf(nx - bf2f(h));
    }
}

// ---------------- embed + diff outputs (LDS transpose, coalesced writes) ----------------
__global__ void embdiff_kernel(const short* __restrict__ xh, const short* __restrict__ xl,
    const int* __restrict__ cls0, const int* __restrict__ cls1, const int* __restrict__ cls2,
    const float* __restrict__ e0, const float* __restrict__ e1, const float* __restrict__ e2,
    float* __restrict__ out)
{
    __shared__ float s[196][65];
    int b = blockIdx.x / 12;
    int dc = (blockIdx.x % 12) * 64;
    int tid = threadIdx.x;
    int dl = tid & 63;
    // embed
    for (int it = 0; it < 49; ++it) {
        int pl = it * 4 + (tid >> 6);
        int p = b * 196 + pl;
        int d = dc + dl;
        s[pl][dl] = e0[(size_t)cls0[p] * DIM + d] + e1[(size_t)cls1[p] * DIM + d]
                  + e2[(size_t)cls2[p] * DIM + d];
    }
    __syncthreads();
    if (tid < 196) {
        for (int d = 0; d < 64; ++d)
            out[((size_t)b * DIM + dc + d) * 196 + tid] = s[tid][d];
    }
    __syncthreads();
    // diff (residual = xh + xl)
    for (int it = 0; it < 49; ++it) {
        int pl = it * 4 + (tid >> 6);
        size_t o = (size_t)(b * 196 + pl) * DIM + dc + dl;
        s[pl][dl] = bf2f(xh[o]) + bf2f(xl[o]);
    }
    __syncthreads();
    if (tid < 196) {
        float* od = out + 2 * (size_t)NP * DIM;
        for (int d = 0; d < 64; ++d)
            od[((size_t)b * DIM + dc + d) * 196 + tid] = s[tid][d];
    }
}

// ---------------- img_sum output ----------------
__global__ void img_kernel(
    const int* __restrict__ cls0, const int* __restrict__ cls1, const int* __restrict__ cls2,
    const float* __restrict__ c0, const float* __restrict__ c1, const float* __restrict__ c2,
    float* __restrict__ out)
{
    __shared__ float s[14][256];
    int bi = blockIdx.x;
    int b = bi / 42; int rem = bi % 42; int ch = rem / 14; int i = rem % 14;
    int tid = threadIdx.x;
    for (int j = 0; j < 14; ++j) {
        int p = b * 196 + i * 14 + j;
        int d = ch * 256 + tid;
        s[j][tid] = c0[(size_t)cls0[p] * DIM + d] + c1[(size_t)cls1[p] * DIM + d]
                  + c2[(size_t)cls2[p] * DIM + d];
    }
    __syncthreads();
    float* oi = out + (size_t)NP * DIM;
    if (tid < 224) {
        int j = tid >> 4, px = tid & 15;
        for (int py = 0; py < 16; ++py)
            oi[(((size_t)b * 3 + ch) * HWD + i * 16 + py) * HWD + tid] = s[j][py * 16 + px];
    }
}

extern "C" void kernel_launch(void* const* d_in, const int* in_sizes, int n_in,
                              void* d_out, int out_size, void* d_ws, size_t ws_size,
                              hipStream_t stream) {
    const float* data = (const float*)d_in[0];
    const float* c0 = (const float*)d_in[1];
    const float* c1 = (const float*)d_in[2];
    const float* c2 = (const float*)d_in[3];
    const float* e0 = (const float*)d_in[4];
    const float* e1 = (const float*)d_in[5];
    const float* e2 = (const float*)d_in[6];
    float* out = (float*)d_out;

    char* w = (char*)d_ws;
    short* xh = (short*)w;    w += (size_t)NP * DIM * 2;      // 9.63 MB
    short* xl = (short*)w;    w += (size_t)NP * DIM * 2;      // 9.63 MB
    short* chB = (short*)w;   w += (size_t)K2 * DIM * 2;      // 12.58 MB
    float* nrm = (float*)w;   w += (size_t)K2 * 4;            // 32 KB
    ull* partB = (ull*)w;     w += (size_t)NP * 128 * 8;      // 6.42 MB
    ull* partS2 = (ull*)w;    w += (size_t)NP * 128 * 8;      // 6.42 MB
    int* cls0 = (int*)w;      w += (size_t)NP * 4;
    int* cls1 = (int*)w;      w += (size_t)NP * 4;
    int* cls2 = (int*)w;      w += (size_t)NP * 4;
    // total ~44.9 MiB

    patchify_split_kernel<<<(NP * DIM) / 256, 256, 0, stream>>>(data, xh, xl);

    // level 0: K=512, NB=128 -> grid (49,4), 8 partials (no swizzle: 4%8!=0)
    cprep_kernel<<<K0 / 4, 256, 0, stream>>>(c0, chB, nrm);
    classify16<<<dim3(NP / 128, K0 / 128), 256, 0, stream>>>(xh, chB, nrm, partB, partS2);
    merge_rescue_update<<<NP / 4, 256, 0, stream>>>(xh, xl, c0, nrm, partB, partS2, 8, cls0);

    // level 1: K=2048, NB=128 -> grid (49,16), 32 partials (swizzled, by-fast)
    cprep_kernel<<<K1 / 4, 256, 0, stream>>>(c1, chB, nrm);
    classify16<<<dim3(NP / 128, K1 / 128), 256, 0, stream>>>(xh, chB, nrm, partB, partS2);
    merge_rescue_update<<<NP / 4, 256, 0, stream>>>(xh, xl, c1, nrm, partB, partS2, 32, cls1);

    // level 2: K=8192, NB=128 -> grid (49,64), 128 partials (swizzled, by-fast)
    cprep_kernel<<<K2 / 4, 256, 0, stream>>>(c2, chB, nrm);
    classify16<<<dim3(NP / 128, K2 / 128), 256, 0, stream>>>(xh, chB, nrm, partB, partS2);
    merge_rescue_update<<<NP / 4, 256, 0, stream>>>(xh, xl, c2, nrm, partB, partS2, 128, cls2);

    embdiff_kernel<<<BATCH * 12, 256, 0, stream>>>(xh, xl, cls0, cls1, cls2, e0, e1, e2, out);
    img_kernel<<<BATCH * 3 * 14, 256, 0, stream>>>(cls0, cls1, cls2, c0, c1, c2, out);
}